// Round 4
// baseline (165.664 us; speedup 1.0000x reference)
//
#include <hip/hip_runtime.h>
#include <math.h>

// Problem constants
#define BATCH 16
#define SEQ   4096
#define HIN   128
#define NST   256
#define HOUT  128
#define CL    32              // chunk length for scan
#define NC    (SEQ/CL)        // 128 chunks
#define ROWS  (BATCH*SEQ)     // 65536
#define KTOT  640             // W K layout: 256 re + 256 im + 128 u
#define NPRE  512             // preL row width: [x_re 256 | x_im 256]

typedef __attribute__((ext_vector_type(8))) short short8;
typedef __attribute__((ext_vector_type(4))) float f32x4;

__device__ inline unsigned short f2bf(float f) {
  union { float f; unsigned u; } v; v.f = f;
  unsigned r = v.u + 0x7FFFu + ((v.u >> 16) & 1u);   // RNE
  return (unsigned short)(r >> 16);
}
__device__ inline float bf2f(unsigned short s) {
  union { unsigned u; float f; } v; v.u = ((unsigned)s) << 16;
  return v.f;
}
__device__ inline float bits2f(unsigned u) {
  union { unsigned u; float f; } v; v.u = u; return v.f;
}

// ------------------------------------------------------------- prep --------
// Wb rows PERMUTED: row r: g=r>>7, w=r&127; n = g*64 + (w&63);
//   w<64 -> gamma*B_re[n], else gamma*B_im[n].
// W = [C_re | -C_im | D] bf16 [128][640].
// lamPk[j][n] = packed bf16 (re lo, im hi) of lambda_n^j, j=0..31.
__global__ __launch_bounds__(256) void k_prep(
    const float* __restrict__ nu_log, const float* __restrict__ theta_log,
    const float* __restrict__ gamma_log,
    const float* __restrict__ Bre, const float* __restrict__ Bim,
    const float* __restrict__ Cre, const float* __restrict__ Cim,
    const float* __restrict__ Dm,
    float* __restrict__ lamre, float* __restrict__ lamim,
    unsigned* __restrict__ lamPk,
    unsigned short* __restrict__ Wb, unsigned short* __restrict__ W) {
  int idx = blockIdx.x*256 + threadIdx.x;
  if (idx < NST) {
    float lm = expf(-expf(nu_log[idx]));
    float th = expf(theta_log[idx]);
    float lr = lm * cosf(th), li = lm * sinf(th);
    lamre[idx] = lr; lamim[idx] = li;
    float pr = 1.f, pi = 0.f;
    for (int j = 0; j < CL; ++j) {
      lamPk[j*NST + idx] = ((unsigned)f2bf(pi) << 16) | (unsigned)f2bf(pr);
      float nr = pr*lr - pi*li;
      float ni = pr*li + pi*lr;
      pr = nr; pi = ni;
    }
  }
  if (idx < 512*HIN) {
    int r = idx >> 7, h = idx & 127;
    int g = r >> 7;
    int w = r & 127;
    int n = g*64 + (w & 63);
    float gm = expf(gamma_log[n]);
    float v = (w < 64) ? Bre[n*HIN + h] : Bim[n*HIN + h];
    Wb[idx] = f2bf(gm * v);
  }
  if (idx < HOUT*KTOT) {
    int o = idx / KTOT, k = idx - o*KTOT;
    float v;
    if (k < NST)        v =  Cre[o*NST + k];
    else if (k < 2*NST) v = -Cim[o*NST + (k - NST)];
    else                v =  Dm[o*HIN + (k - 2*NST)];
    W[idx] = f2bf(v);
  }
}

// -------- bu GEMM (MFMA) + fused local-prefix + chunk-carry epilogue -------
// grid ROWS/128 = 512. Block: 128 rows x 512 cols (4 col-groups).
// Epilogue v2: ALL 4 chunks staged as bf16 (33.8 KB, fits union) and scanned
// in ONE phase with all 256 threads (was 2 phases x 128 threads idle-half).
// Barriers/group 6 -> 4; serial-phase count per block 8 -> 4.
union SharedBu {
  unsigned short B[128][136];     // 34.8 KB group staging
  unsigned short stgb[4][32][132]; // 33.8 KB carry stage (4 chunks, bf16)
};
__global__ __launch_bounds__(256) void k_bu(
    const float* __restrict__ u, const unsigned short* __restrict__ Wb,
    const float* __restrict__ lamre, const float* __restrict__ lamim,
    unsigned short* __restrict__ preL,
    float* __restrict__ S_re, float* __restrict__ S_im) {
  __shared__ unsigned short Asl[128][136];   // resident whole kernel
  __shared__ SharedBu sh;
  int tid = threadIdx.x;
  int row0 = blockIdx.x * 128;
  int wid = tid >> 6, lane = tid & 63;
  int lm = lane & 15, lq = lane >> 4;
  int m0 = (wid >> 1) * 64, n0 = (wid & 1) * 64;
  int b = row0 >> 12;                 // / SEQ
  int cbase = (row0 & 4095) >> 5;     // / CL
  // stage A: 128 rows x 128 f32 -> bf16
#pragma unroll
  for (int cc = 0; cc < 8; ++cc) {
    int ch = cc*256 + tid;
    int r = ch >> 4, h0 = (ch & 15) * 8;
    const float* src = u + (size_t)(row0 + r)*HIN + h0;
    float4 v0 = *(const float4*)src;
    float4 v1 = *(const float4*)(src + 4);
    unsigned short o[8];
    o[0]=f2bf(v0.x); o[1]=f2bf(v0.y); o[2]=f2bf(v0.z); o[3]=f2bf(v0.w);
    o[4]=f2bf(v1.x); o[5]=f2bf(v1.y); o[6]=f2bf(v1.z); o[7]=f2bf(v1.w);
    *(short8*)&Asl[r][h0] = *(const short8*)o;
  }
  for (int g = 0; g < 4; ++g) {
    __syncthreads();    // A ready (g=0) / prior scan's stgb reads done (g>0)
#pragma unroll
    for (int cc = 0; cc < 8; ++cc) {
      int ch = cc*256 + tid;
      int r = ch >> 4, h0 = (ch & 15) * 8;
      *(short8*)&sh.B[r][h0] = *(const short8*)&Wb[(size_t)(g*128 + r)*HIN + h0];
    }
    __syncthreads();
    f32x4 acc[4][4];
#pragma unroll
    for (int i = 0; i < 4; ++i)
#pragma unroll
      for (int j = 0; j < 4; ++j) acc[i][j] = (f32x4)0.f;
#pragma unroll
    for (int ks = 0; ks < 4; ++ks) {
      int k0 = ks*32 + lq*8;
      short8 a[4], bb[4];
#pragma unroll
      for (int i = 0; i < 4; ++i) a[i] = *(const short8*)&Asl[m0 + i*16 + lm][k0];
#pragma unroll
      for (int j = 0; j < 4; ++j) bb[j] = *(const short8*)&sh.B[n0 + j*16 + lm][k0];
#pragma unroll
      for (int i = 0; i < 4; ++i)
#pragma unroll
        for (int j = 0; j < 4; ++j)
          acc[i][j] = __builtin_amdgcn_mfma_f32_16x16x32_bf16(a[i], bb[j], acc[i][j], 0, 0, 0);
    }
    __syncthreads();   // all waves' B reads done before stgb overwrite (union)
    // stage acc (all 4 chunks) to LDS as bf16
#pragma unroll
    for (int i = 0; i < 4; ++i)
#pragma unroll
      for (int j = 0; j < 4; ++j)
#pragma unroll
        for (int r = 0; r < 4; ++r) {
          int row = m0 + i*16 + lq*4 + r;            // 0..127
          sh.stgb[row >> 5][row & 31][n0 + j*16 + lm] = f2bf(acc[i][j][r]);
        }
    __syncthreads();   // stgb ready
    // one scan phase, all 256 threads: chunk = tid>>6, state = tid&63
    {
      int ck = tid >> 6, nl = tid & 63;
      int ng = g*64 + nl;
      float lr = lamre[ng], li = lamim[ng];
      float rr[CL], ri[CL];
#pragma unroll
      for (int t = 0; t < CL; ++t) {
        rr[t] = bf2f(sh.stgb[ck][t][nl]);
        ri[t] = bf2f(sh.stgb[ck][t][64 + nl]);
      }
      int rowb = row0 + ck*32;
      unsigned short* pl = preL + (size_t)rowb*NPRE;
      float sr = 0.f, si = 0.f;
#pragma unroll
      for (int t = 0; t < CL; ++t) {
        pl[ng]       = f2bf(sr);     // local prefix BEFORE step t
        pl[NST + ng] = f2bf(si);
        float nr = lr*sr - li*si + rr[t];
        float ni = lr*si + li*sr + ri[t];
        sr = nr; si = ni; pl += NPRE;
      }
      int c = cbase + ck;
      int idx = (b*NC + c)*NST + ng;
      S_re[idx] = sr; S_im[idx] = si;
    }
  }
}

// ---------------- single-kernel scan of chunk carries -> X0 ----------------
// Replaces k_carry2 + k_final (removes G round-trip + one launch gap).
// grid 64 blocks x 64 threads: block (b, quarter-of-n); thread n runs the
// full 128-chunk serial carry scan with ping-pong 16-chunk prefetch.
__global__ __launch_bounds__(64) void k_scan(
    const float* __restrict__ S_re, const float* __restrict__ S_im,
    const float* __restrict__ lamre, const float* __restrict__ lamim,
    unsigned* __restrict__ X0Pk) {
  int b = blockIdx.x >> 2;
  int n = (blockIdx.x & 3) * 64 + threadIdx.x;
  float ar = lamre[n], ai = lamim[n];
#pragma unroll
  for (int s = 0; s < 5; ++s) { float nr = ar*ar - ai*ai, ni = 2.f*ar*ai; ar = nr; ai = ni; } // lam^32
  const float* Sr = S_re + (size_t)b*NC*NST + n;
  const float* Si = S_im + (size_t)b*NC*NST + n;
  unsigned* Xp = X0Pk + (size_t)b*NC*NST + n;
  float Are[16], Aim[16], Bre[16], Bim[16];
#pragma unroll
  for (int cc = 0; cc < 16; ++cc) { Are[cc] = Sr[cc*NST]; Aim[cc] = Si[cc*NST]; }
  float xr = 0.f, xi = 0.f;
#pragma unroll
  for (int seg = 0; seg < 8; ++seg) {
    if (seg < 7) {     // prefetch next segment into the other buffer
      const float* pr = Sr + (size_t)(seg+1)*16*NST;
      const float* pi = Si + (size_t)(seg+1)*16*NST;
      if (seg & 1) {
#pragma unroll
        for (int cc = 0; cc < 16; ++cc) { Are[cc] = pr[cc*NST]; Aim[cc] = pi[cc*NST]; }
      } else {
#pragma unroll
        for (int cc = 0; cc < 16; ++cc) { Bre[cc] = pr[cc*NST]; Bim[cc] = pi[cc*NST]; }
      }
    }
#pragma unroll
    for (int cc = 0; cc < 16; ++cc) {
      Xp[(size_t)(seg*16 + cc)*NST] = ((unsigned)f2bf(xi) << 16) | (unsigned)f2bf(xr);
      float cr = (seg & 1) ? Bre[cc] : Are[cc];
      float ci = (seg & 1) ? Bim[cc] : Aim[cc];
      float nr = ar*xr - ai*xi + cr;
      float ni = ar*xi + ai*xr + ci;
      xr = nr; xi = ni;
    }
  }
}

// -------------- output GEMM: LDS-staged A with fix-up at staging -----------
// (verbatim round-3 text — harness-verified at 162.9 us.)
__global__ __launch_bounds__(256) void k_out2(
    const unsigned short* __restrict__ preL, const float* __restrict__ u,
    const unsigned short* __restrict__ W,
    const unsigned* __restrict__ lamPk, const unsigned* __restrict__ X0Pk,
    float* __restrict__ y) {
  __shared__ unsigned short Asl[128][136];
  __shared__ unsigned short Bsl[128][136];
  int tid = threadIdx.x;
  int row0 = blockIdx.x * 128;
  int wid = tid >> 6, lane = tid & 63;
  int lm = lane & 15, lq = lane >> 4;
  int m0 = wid * 32;
  f32x4 acc[2][8];
#pragma unroll
  for (int i = 0; i < 2; ++i)
#pragma unroll
    for (int j = 0; j < 8; ++j) acc[i][j] = (f32x4)0.f;
  for (int s = 0; s < 5; ++s) {
    __syncthreads();   // prior MFMA LDS reads done before restage
    // stage B: W[:, s*128 .. s*128+128)
#pragma unroll
    for (int cc = 0; cc < 8; ++cc) {
      int ch = cc*256 + tid;
      int r = ch >> 4, h0 = (ch & 15) * 8;
      *(short8*)&Bsl[r][h0] = *(const short8*)&W[(size_t)r*KTOT + s*128 + h0];
    }
    // stage A: 128 rows x 128 cols, coalesced, fix-up applied inline
    if (s < 4) {
#pragma unroll
      for (int cc = 0; cc < 8; ++cc) {
        int ch = cc*256 + tid;
        int r = ch >> 4, h0 = (ch & 15) * 8;
        int grow = row0 + r;
        int j32 = r & 31;            // row0 % 128 == 0
        int cidx = grow >> 5;
        int n = ((s & 1) << 7) + h0; // state index of first element
        short8 loc = *(const short8*)&preL[(size_t)grow*NPRE + s*128 + h0];
        uint4 lp0 = *(const uint4*)&lamPk[j32*NST + n];
        uint4 lp1 = *(const uint4*)&lamPk[j32*NST + n + 4];
        uint4 xp0 = *(const uint4*)&X0Pk[(size_t)cidx*NST + n];
        uint4 xp1 = *(const uint4*)&X0Pk[(size_t)cidx*NST + n + 4];
        unsigned lps[8] = {lp0.x, lp0.y, lp0.z, lp0.w, lp1.x, lp1.y, lp1.z, lp1.w};
        unsigned xps[8] = {xp0.x, xp0.y, xp0.z, xp0.w, xp1.x, xp1.y, xp1.z, xp1.w};
        unsigned short o[8];
#pragma unroll
        for (int e = 0; e < 8; ++e) {
          float lr = bits2f(lps[e] << 16);
          float li = bits2f(lps[e] & 0xFFFF0000u);
          float xr = bits2f(xps[e] << 16);
          float xi = bits2f(xps[e] & 0xFFFF0000u);
          float lv = bf2f((unsigned short)loc[e]);
          float v = (s < 2) ? (lv + lr*xr - li*xi)
                            : (lv + lr*xi + li*xr);
          o[e] = f2bf(v);
        }
        *(short8*)&Asl[r][h0] = *(const short8*)o;
      }
    } else {
#pragma unroll
      for (int cc = 0; cc < 8; ++cc) {
        int ch = cc*256 + tid;
        int r = ch >> 4, h0 = (ch & 15) * 8;
        const float* src = u + (size_t)(row0 + r)*HIN + h0;
        float4 v0 = *(const float4*)src;
        float4 v1 = *(const float4*)(src + 4);
        unsigned short o[8];
        o[0]=f2bf(v0.x); o[1]=f2bf(v0.y); o[2]=f2bf(v0.z); o[3]=f2bf(v0.w);
        o[4]=f2bf(v1.x); o[5]=f2bf(v1.y); o[6]=f2bf(v1.z); o[7]=f2bf(v1.w);
        *(short8*)&Asl[r][h0] = *(const short8*)o;
      }
    }
    __syncthreads();
#pragma unroll
    for (int ks = 0; ks < 4; ++ks) {
      int k0 = ks*32 + lq*8;
      short8 a[2], bb[8];
#pragma unroll
      for (int i = 0; i < 2; ++i) a[i] = *(const short8*)&Asl[m0 + i*16 + lm][k0];
#pragma unroll
      for (int j = 0; j < 8; ++j) bb[j] = *(const short8*)&Bsl[j*16 + lm][k0];
#pragma unroll
      for (int i = 0; i < 2; ++i)
#pragma unroll
        for (int j = 0; j < 8; ++j)
          acc[i][j] = __builtin_amdgcn_mfma_f32_16x16x32_bf16(a[i], bb[j], acc[i][j], 0, 0, 0);
    }
  }
#pragma unroll
  for (int i = 0; i < 2; ++i)
#pragma unroll
    for (int j = 0; j < 8; ++j)
#pragma unroll
      for (int r = 0; r < 4; ++r)
        y[(size_t)(row0 + m0 + i*16 + lq*4 + r)*HOUT + j*16 + lm] = acc[i][j][r];
}

// --------------------------------------------------------------------------
extern "C" void kernel_launch(void* const* d_in, const int* in_sizes, int n_in,
                              void* d_out, int out_size, void* d_ws, size_t ws_size,
                              hipStream_t stream) {
  const float* u         = (const float*)d_in[0];
  const float* nu_log    = (const float*)d_in[1];
  const float* theta_log = (const float*)d_in[2];
  const float* gamma_log = (const float*)d_in[3];
  const float* B_re      = (const float*)d_in[4];
  const float* B_im      = (const float*)d_in[5];
  const float* C_re      = (const float*)d_in[6];
  const float* C_im      = (const float*)d_in[7];
  const float* Dm        = (const float*)d_in[8];
  float* y = (float*)d_out;
  char* ws = (char*)d_ws;

  size_t off = 0;
  float* lamre = (float*)(ws + off);            off += 1024;
  float* lamim = (float*)(ws + off);            off += 1024;
  unsigned* lamPk = (unsigned*)(ws + off);      off += 32768;       // 32x256 u32
  unsigned short* Wb = (unsigned short*)(ws + off); off += 131072;  // 512x128 bf16
  unsigned short* W  = (unsigned short*)(ws + off); off += 163840;  // 128x640 bf16
  unsigned short* preL = (unsigned short*)(ws + off); off += (size_t)ROWS*NPRE*2; // 64 MB
  float* S_re = (float*)(ws + off);             off += 2097152;
  float* S_im = (float*)(ws + off);             off += 2097152;
  unsigned* X0Pk = (unsigned*)(ws + off);       off += 2097152;     // 2048x256 u32

  k_prep<<<320, 256, 0, stream>>>(nu_log, theta_log, gamma_log, B_re, B_im,
                                  C_re, C_im, Dm, lamre, lamim, lamPk, Wb, W);
  k_bu<<<ROWS/128, 256, 0, stream>>>(u, Wb, lamre, lamim, preL, S_re, S_im);
  k_scan<<<64, 64, 0, stream>>>(S_re, S_im, lamre, lamim, X0Pk);
  k_out2<<<ROWS/128, 256, 0, stream>>>(preL, u, W, lamPk, X0Pk, y);
}